// Round 10
// baseline (294.572 us; speedup 1.0000x reference)
//
#include <hip/hip_runtime.h>
#include <hip/hip_bf16.h>

#define NTOK 2048
#define EMBED 512
#define NHEADS 8
#define HD 64
#define NBINS 512
#define MAXSEL 256

typedef unsigned short u16;
typedef unsigned int u32;

__device__ __forceinline__ float lof(u32 u){ return __uint_as_float(u << 16); }
__device__ __forceinline__ float hif(u32 u){ return __uint_as_float(u & 0xffff0000u); }
__device__ __forceinline__ float bf2f(u16 u){ return __uint_as_float(((u32)u) << 16); }
__device__ __forceinline__ u16 f2b(float f){
    __hip_bfloat16 h = __float2bfloat16(f);
    return *(u16*)&h;
}
__device__ __forceinline__ u32 pack2(float lo, float hi){
    return (u32)f2b(lo) | ((u32)f2b(hi) << 16);
}
__device__ __forceinline__ void fma8(const float* x, u32 ux, u32 uy, u32 uz, u32 uw, float& a){
    a += x[0]*lof(ux) + x[1]*hif(ux) + x[2]*lof(uy) + x[3]*hif(uy)
       + x[4]*lof(uz) + x[5]*hif(uz) + x[6]*lof(uw) + x[7]*hif(uw);
}

// Inline per-block dtype sniff: read 64 even u16s of the tensor as bf16.
// f32 data -> low mantissa halves -> random bf16 exponents -> max>100 w.p. ~1.
// bf16 data here (|x|<6) -> max<10. All threads same samples -> uniform branch.
__device__ __forceinline__ u32 sniffp(const void* p){
    const u16* s = (const u16*)p;
    float m = 0.f;
    #pragma unroll
    for (int k=0; k<64; k++) m = fmaxf(m, fabsf(bf2f(s[2*k])));
    return (m > 100.f) ? 1u : 0u;
}

// unpack 8 bf16 (uint4) -> 2x float4
__device__ __forceinline__ void ub2(const uint4& u, float4& f0, float4& f1){
    f0 = make_float4(lof(u.x), hif(u.x), lof(u.y), hif(u.y));
    f1 = make_float4(lof(u.z), hif(u.z), lof(u.w), hif(u.w));
}

// 8-k dot: x (2x float4 from LDS broadcast) . a (2x float4 W in registers)
__device__ __forceinline__ float dot8(const float4& x0, const float4& x1,
                                      const float4& a0, const float4& a1){
    float s;
    s  = x0.x*a0.x; s += x0.y*a0.y; s += x0.z*a0.z; s += x0.w*a0.w;
    s += x1.x*a1.x; s += x1.y*a1.y; s += x1.z*a1.z; s += x1.w*a1.w;
    return s;
}

// 16-k dot step for two output columns sharing one X broadcast read.
// (used by oproj — round-5/7 verified)
__device__ __forceinline__ void fma16x2(const float* xp,
    const float4& a0, const float4& a1, const float4& a2, const float4& a3,
    const float4& b0, const float4& b1, const float4& b2, const float4& b3,
    float& A, float& B)
{
    float4 x0 = *(const float4*)(xp);
    float4 x1 = *(const float4*)(xp+4);
    float4 x2 = *(const float4*)(xp+8);
    float4 x3 = *(const float4*)(xp+12);
    A += x0.x*a0.x; A += x0.y*a0.y; A += x0.z*a0.z; A += x0.w*a0.w;
    A += x1.x*a1.x; A += x1.y*a1.y; A += x1.z*a1.z; A += x1.w*a1.w;
    A += x2.x*a2.x; A += x2.y*a2.y; A += x2.z*a2.z; A += x2.w*a2.w;
    A += x3.x*a3.x; A += x3.y*a3.y; A += x3.z*a3.z; A += x3.w*a3.w;
    B += x0.x*b0.x; B += x0.y*b0.y; B += x0.z*b0.z; B += x0.w*b0.w;
    B += x1.x*b1.x; B += x1.y*b1.y; B += x1.z*b1.z; B += x1.w*b1.w;
    B += x2.x*b2.x; B += x2.y*b2.y; B += x2.z*b2.z; B += x2.w*b2.w;
    B += x3.x*b3.x; B += x3.y*b3.y; B += x3.z*b3.z; B += x3.w*b3.w;
}

// ============ K1: QKV projection + per-head norm + centroid bins ============
// grid (256, 3): 8 tokens/block, y: 0=Q 1=K 2=V. block 256 (4 waves).
// GEMM v10 — k-split across wave-pairs: waves 0-1 compute k in [0,256),
// waves 2-3 k in [256,512); each thread owns 4 cols (tp,+128,+256,+384) over
// its k-half. X-broadcast LDS instrs per wave HALVE (the measured dominant
// cost, ~147k cyc/CU) while W bytes + W instr count + per-instr line-touch
// stay exactly invariant (the invariant every failed restructure broke).
// Pair-1 dumps partials to ubuf (coalesced b32); pair-0 combines + bias +
// writes ps. Scan: round-9 verified (stride-68 b128 row reads).
__global__ __launch_bounds__(256) void projqkv_kernel(
    const void* __restrict__ Xq, const void* __restrict__ Xk, const void* __restrict__ Xv,
    const void* __restrict__ Wq, const void* __restrict__ bq,
    const void* __restrict__ Wk, const void* __restrict__ bk,
    const void* __restrict__ Wv, const void* __restrict__ bv,
    const void* __restrict__ cen,
    void* __restrict__ outQ,                 // d_out: normalized Q staging (out dtype)
    u16* __restrict__ Kb, u16* __restrict__ Vb,
    u16* __restrict__ qbin, u16* __restrict__ kbin)
{
    int which = blockIdx.y;
    const void *X, *W, *Bb;
    if (which==0){ X=Xq; W=Wq; Bb=bq; }
    else if (which==1){ X=Xk; W=Wk; Bb=bk; }
    else { X=Xv; W=Wv; Bb=bv; }
    u32 fx = sniffp(X), fw = sniffp(W), fb = sniffp(Bb);
    int r0 = blockIdx.x * 8;
    int t = threadIdx.x;

    __shared__ __align__(16) float ubuf[4608];  // GEMM partials [32][132] / scan tiles [64][68]
    __shared__ __align__(16) float ps[64*68];   // results [(tok*8+head)][68]; first 4128
                                                // floats alias X-stage [8][516] during GEMM
    __shared__ float nrm2[64][4];
    __shared__ float invn[64];
    __shared__ float bvl[64][8];
    __shared__ int   bil[64][8];

    float* xstage = ps;
    // Phase A: stage X tile (8 x 512), coalesced 16B/lane
    for (int i=t; i<1024; i+=256){
        int row = i>>7, c4 = i&127;
        float4 v;
        if (!fx){
            const u32* xp = (const u32*)((const u16*)X + (size_t)(r0+row)*EMBED);
            u32 a = xp[c4*2], b = xp[c4*2+1];
            v = make_float4(lof(a), hif(a), lof(b), hif(b));
        } else {
            v = ((const float4*)((const float*)X + (size_t)(r0+row)*EMBED))[c4];
        }
        *(float4*)(xstage + row*516 + c4*4) = v;
    }
    __syncthreads();                     // xstage ready

    int tp = t & 127;                    // cols tp, tp+128, tp+256, tp+384
    int kh = t >> 7;                     // k-half: 0 -> [0,256), 1 -> [256,512)
    int kbase = kh << 8;

    float acc4[8][4];
    #pragma unroll
    for (int r=0;r<8;r++){ acc4[r][0]=0.f; acc4[r][1]=0.f; acc4[r][2]=0.f; acc4[r][3]=0.f; }

    if (fw){
        const float* w0 = (const float*)W + (size_t)(tp      )*EMBED + kbase;
        const float* w1 = (const float*)W + (size_t)(tp + 128)*EMBED + kbase;
        const float* w2 = (const float*)W + (size_t)(tp + 256)*EMBED + kbase;
        const float* w3 = (const float*)W + (size_t)(tp + 384)*EMBED + kbase;
        float4 a00 = *(const float4*)(w0+0), a01 = *(const float4*)(w0+4);
        float4 a10 = *(const float4*)(w1+0), a11 = *(const float4*)(w1+4);
        float4 a20 = *(const float4*)(w2+0), a21 = *(const float4*)(w2+4);
        float4 a30 = *(const float4*)(w3+0), a31 = *(const float4*)(w3+4);
        #pragma unroll 1
        for (int k0=0; k0<256; k0+=8){
            float4 b00,b01,b10,b11,b20,b21,b30,b31;
            if (k0+8 < 256){
                b00 = *(const float4*)(w0+k0+8);  b01 = *(const float4*)(w0+k0+12);
                b10 = *(const float4*)(w1+k0+8);  b11 = *(const float4*)(w1+k0+12);
                b20 = *(const float4*)(w2+k0+8);  b21 = *(const float4*)(w2+k0+12);
                b30 = *(const float4*)(w3+k0+8);  b31 = *(const float4*)(w3+k0+12);
            }
            #pragma unroll
            for (int r=0;r<8;r++){
                const float* xp = xstage + r*516 + kbase + k0;   // uniform broadcast
                float4 x0 = *(const float4*)(xp);
                float4 x1 = *(const float4*)(xp+4);
                acc4[r][0] += dot8(x0,x1,a00,a01);
                acc4[r][1] += dot8(x0,x1,a10,a11);
                acc4[r][2] += dot8(x0,x1,a20,a21);
                acc4[r][3] += dot8(x0,x1,a30,a31);
            }
            if (k0+8 < 256){
                a00=b00; a01=b01; a10=b10; a11=b11;
                a20=b20; a21=b21; a30=b30; a31=b31;
            }
        }
    } else {
        const uint4* w0 = (const uint4*)((const u16*)W + (size_t)(tp      )*EMBED + kbase);
        const uint4* w1 = (const uint4*)((const u16*)W + (size_t)(tp + 128)*EMBED + kbase);
        const uint4* w2 = (const uint4*)((const u16*)W + (size_t)(tp + 256)*EMBED + kbase);
        const uint4* w3 = (const uint4*)((const u16*)W + (size_t)(tp + 384)*EMBED + kbase);
        uint4 u0 = w0[0], u1 = w1[0], u2 = w2[0], u3 = w3[0];
        #pragma unroll 1
        for (int k0=0; k0<256; k0+=8){
            int i8 = k0>>3;
            uint4 v0,v1,v2,v3;
            if (k0+8 < 256){ v0 = w0[i8+1]; v1 = w1[i8+1]; v2 = w2[i8+1]; v3 = w3[i8+1]; }
            float4 a00,a01,a10,a11,a20,a21,a30,a31;
            ub2(u0,a00,a01); ub2(u1,a10,a11); ub2(u2,a20,a21); ub2(u3,a30,a31);
            #pragma unroll
            for (int r=0;r<8;r++){
                const float* xp = xstage + r*516 + kbase + k0;
                float4 x0 = *(const float4*)(xp);
                float4 x1 = *(const float4*)(xp+4);
                acc4[r][0] += dot8(x0,x1,a00,a01);
                acc4[r][1] += dot8(x0,x1,a10,a11);
                acc4[r][2] += dot8(x0,x1,a20,a21);
                acc4[r][3] += dot8(x0,x1,a30,a31);
            }
            if (k0+8 < 256){ u0=v0; u1=v1; u2=v2; u3=v3; }
        }
    }
    // pair-1 dumps partials (coalesced stride-1 b32, conflict-free)
    if (kh){
        #pragma unroll
        for (int r=0;r<8;r++){
            #pragma unroll
            for (int c=0;c<4;c++)
                ubuf[(r*4+c)*132 + tp] = acc4[r][c];
        }
    }
    __syncthreads();                     // xstage reads done + partials visible
    if (!kh){
        float bc0, bc1, bc2, bc3;
        if (fb){
            const float* bp = (const float*)Bb;
            bc0=bp[tp]; bc1=bp[tp+128]; bc2=bp[tp+256]; bc3=bp[tp+384];
        } else {
            const u16* bp = (const u16*)Bb;
            bc0=bf2f(bp[tp]); bc1=bf2f(bp[tp+128]); bc2=bf2f(bp[tp+256]); bc3=bf2f(bp[tp+384]);
        }
        int cw = tp & 63, hb = tp >> 6;          // heads hb, hb+2, hb+4, hb+6
        #pragma unroll
        for (int r=0;r<8;r++){
            ps[(r*8 + hb    )*68 + cw] = (acc4[r][0] + ubuf[(r*4+0)*132 + tp]) + bc0;
            ps[(r*8 + hb + 2)*68 + cw] = (acc4[r][1] + ubuf[(r*4+1)*132 + tp]) + bc1;
            ps[(r*8 + hb + 4)*68 + cw] = (acc4[r][2] + ubuf[(r*4+2)*132 + tp]) + bc2;
            ps[(r*8 + hb + 6)*68 + cw] = (acc4[r][3] + ubuf[(r*4+3)*132 + tp]) + bc3;
        }
    }
    __syncthreads();

    if (which == 2){
        // V: store raw bf16, 16 elems/thread
        int hr = t>>2, q4 = t&3;
        int row = hr>>3, head = hr&7;
        const float* src = ps + hr*68 + q4*16;
        u16* dst = Vb + (size_t)(r0+row)*EMBED + head*64 + q4*16;
        #pragma unroll
        for (int j8=0;j8<2;j8++){
            uint4 v;
            v.x = pack2(src[j8*8+0],src[j8*8+1]); v.y = pack2(src[j8*8+2],src[j8*8+3]);
            v.z = pack2(src[j8*8+4],src[j8*8+5]); v.w = pack2(src[j8*8+6],src[j8*8+7]);
            ((uint4*)dst)[j8] = v;
        }
        return;
    }

    // ---------- centroid scan: register-tiled LDS GEMM + argmax, tile prefetch ----------
    u32 fc = sniffp(cen);
    int rg = t>>3, cg = t&7;             // rows {2rg, 2rg+1}, cents cg*8..cg*8+7 per tile
    float best[2] = {-3.4e38f,-3.4e38f};
    int   bidx[2] = {0,0};
    float cpre[16];
    #pragma unroll
    for (int it=0; it<16; it++){
        int e = t + it*256, j = e>>6, k = e&63;
        cpre[it] = fc ? ((const float*)cen)[(size_t)j*HD + k]
                      : bf2f(((const u16*)cen)[(size_t)j*HD + k]);
    }
    for (int tt=0; tt<8; tt++){
        __syncthreads();                 // prev tile consumed (tt=0: ubuf partials consumed)
        #pragma unroll
        for (int it=0; it<16; it++){
            int e = t + it*256, j = e>>6, k = e&63;
            ubuf[k*68 + j] = cpre[it];
        }
        if (tt < 7){
            #pragma unroll
            for (int it=0; it<16; it++){
                int e = t + it*256, j = e>>6, k = e&63;
                int gj = (tt+1)*64 + j;
                cpre[it] = fc ? ((const float*)cen)[(size_t)gj*HD + k]
                              : bf2f(((const u16*)cen)[(size_t)gj*HD + k]);
            }
        }
        __syncthreads();
        float acc[2][8];
        #pragma unroll
        for (int j=0;j<2;j++)
            #pragma unroll
            for (int c=0;c<8;c++) acc[j][c]=0.f;
        const float* pr0 = ps + (2*rg)*68;
        const float* pr1 = pr0 + 68;
        #pragma unroll 1
        for (int k4=0;k4<64;k4+=4){
            float4 ra = *(const float4*)(pr0 + k4);     // b128 row reads
            float4 rb = *(const float4*)(pr1 + k4);
            const float* cbase = ubuf + k4*68 + cg*8;
            #define SCANK(OFF, AX, BX) { \
                const float4* cp = (const float4*)(cbase + (OFF)); \
                float4 c0 = cp[0], c1 = cp[1]; \
                acc[0][0]+=(AX)*c0.x; acc[0][1]+=(AX)*c0.y; acc[0][2]+=(AX)*c0.z; acc[0][3]+=(AX)*c0.w; \
                acc[0][4]+=(AX)*c1.x; acc[0][5]+=(AX)*c1.y; acc[0][6]+=(AX)*c1.z; acc[0][7]+=(AX)*c1.w; \
                acc[1][0]+=(BX)*c0.x; acc[1][1]+=(BX)*c0.y; acc[1][2]+=(BX)*c0.z; acc[1][3]+=(BX)*c0.w; \
                acc[1][4]+=(BX)*c1.x; acc[1][5]+=(BX)*c1.y; acc[1][6]+=(BX)*c1.z; acc[1][7]+=(BX)*c1.w; }
            SCANK(0,   ra.x, rb.x)
            SCANK(68,  ra.y, rb.y)
            SCANK(136, ra.z, rb.z)
            SCANK(204, ra.w, rb.w)
            #undef SCANK
        }
        #pragma unroll
        for (int j=0;j<2;j++){
            #pragma unroll
            for (int c=0;c<8;c++){
                int gi = tt*64 + cg*8 + c;   // ascending in-thread -> strict > keeps first
                if (acc[j][c] > best[j]){ best[j]=acc[j][c]; bidx[j]=gi; }
            }
        }
    }
    bvl[2*rg  ][cg]=best[0]; bil[2*rg  ][cg]=bidx[0];
    bvl[2*rg+1][cg]=best[1]; bil[2*rg+1][cg]=bidx[1];
    {
        int hr = t>>2, q4 = t&3;
        const float* src = ps + hr*68 + q4*16;
        float ss=0.f;
        #pragma unroll
        for (int d=0;d<16;d++) ss += src[d]*src[d];
        nrm2[hr][q4]=ss;
    }
    __syncthreads();
    if (t < 64){
        int hr = t;
        invn[hr] = 1.f / fmaxf(sqrtf(nrm2[hr][0]+nrm2[hr][1]+nrm2[hr][2]+nrm2[hr][3]), 1e-12f);
        float bv = bvl[hr][0]; int bi = bil[hr][0];
        #pragma unroll
        for (int g=1; g<8; g++){         // disjoint index sets: (>, ==&&<) merge = np.argmax
            float ov = bvl[hr][g]; int oi = bil[hr][g];
            if (ov > bv || (ov == bv && oi < bi)){ bv = ov; bi = oi; }
        }
        u16* bins = (which==0) ? qbin : kbin;
        int token = r0 + (hr>>3), head = hr&7;
        bins[head*NTOK + token] = (u16)bi;
    }
    __syncthreads();
    {
        int hr = t>>2, q4 = t&3;
        float inv = invn[hr];
        const float* src = ps + hr*68 + q4*16;
        int row = hr>>3, head = hr&7;
        size_t off = (size_t)(r0+row)*EMBED + head*64 + q4*16;
        if (which == 1){
            u16* dst = Kb + off;
            #pragma unroll
            for (int j8=0;j8<2;j8++){
                uint4 v;
                v.x = pack2(src[j8*8+0]*inv, src[j8*8+1]*inv);
                v.y = pack2(src[j8*8+2]*inv, src[j8*8+3]*inv);
                v.z = pack2(src[j8*8+4]*inv, src[j8*8+5]*inv);
                v.w = pack2(src[j8*8+6]*inv, src[j8*8+7]*inv);
                ((uint4*)dst)[j8] = v;
            }
        } else if (!fx){
            u16* dst = (u16*)outQ + off;
            #pragma unroll
            for (int j8=0;j8<2;j8++){
                uint4 v;
                v.x = pack2(src[j8*8+0]*inv, src[j8*8+1]*inv);
                v.y = pack2(src[j8*8+2]*inv, src[j8*8+3]*inv);
                v.z = pack2(src[j8*8+4]*inv, src[j8*8+5]*inv);
                v.w = pack2(src[j8*8+6]*inv, src[j8*8+7]*inv);
                ((uint4*)dst)[j8] = v;
            }
        } else {
            float* dst = (float*)outQ + off;
            #pragma unroll
            for (int j4=0;j4<4;j4++){
                float4 v = make_float4(src[j4*4+0]*inv, src[j4*4+1]*inv,
                                       src[j4*4+2]*inv, src[j4*4+3]*inv);
                ((float4*)dst)[j4] = v;
            }
        }
    }
}

// ============ K2: attention ============
// grid 2048 (one block per query token), 4 waves x 2 heads. Qb read from d_out row q,
// AO written back to the same row (race-free).
// v2 (round-8 verified): sel/sc wave-local -> no block barriers after qs;
// register-softmax fast path for L<=64 (typical L ~ Poisson(12)); LDS slow
// path for L>64 / fallback.
__global__ __launch_bounds__(256) void attn_kernel(
    const void* __restrict__ query,
    const u16* __restrict__ Kb, const u16* __restrict__ Vb,
    const u16* __restrict__ qbin, const u16* __restrict__ kbin,
    void* __restrict__ out)
{
    u32 fq = sniffp(query);
    int q = blockIdx.x, t = threadIdx.x;
    int wave = t>>6, lane = t&63;
    __shared__ float qs[512];
    __shared__ float sc[4][256];
    __shared__ u16   sel[4][256];

    if (!fq){
        u32 u = ((const u32*)out)[(size_t)q*256 + t];
        qs[2*t] = lof(u); qs[2*t+1] = hif(u);
    } else {
        float2 f = ((const float2*)out)[(size_t)q*256 + t];
        qs[2*t] = f.x; qs[2*t+1] = f.y;
    }
    __syncthreads();                 // qs ready (only block-wide dependency)

    for (int hh=0; hh<2; hh++){
        int h = wave*2 + hh;
        int myqb = qbin[h*NTOK + q];
        const uint4* kbp = (const uint4*)(kbin + h*NTOK + lane*32);
        u32 fl = 0;
        #pragma unroll
        for (int w4=0; w4<4; w4++){
            uint4 kw = kbp[w4];
            u32 arr[4] = {kw.x, kw.y, kw.z, kw.w};
            #pragma unroll
            for (int e=0;e<4;e++){
                int b0 = (int)(arr[e] & 0xffff), b1 = (int)(arr[e] >> 16);
                int d0 = (myqb - b0) & (NBINS-1), d1 = (myqb - b1) & (NBINS-1);
                if (d0 <= 1 || d0 >= NBINS-1) fl |= 1u << (w4*8 + e*2);
                if (d1 <= 1 || d1 >= NBINS-1) fl |= 1u << (w4*8 + e*2 + 1);
            }
        }
        int cnt = __popc(fl);
        int sum = cnt;
        #pragma unroll
        for (int off=1; off<64; off<<=1){
            int v = __shfl_up(sum, off, 64);
            if (lane >= off) sum += v;
        }
        int total = __shfl(sum, 63, 64);
        int r = sum - cnt;
        if (total){
            u32 f2 = fl;
            while (f2){
                int j = __ffs(f2) - 1; f2 &= f2 - 1;
                if (r < MAXSEL) sel[wave][r] = (u16)(lane*32 + j);
                r++;
            }
        } else {
            #pragma unroll
            for (int kq=0;kq<4;kq++) sel[wave][lane*4+kq] = (u16)(lane*4+kq);
        }
        int L = total ? min(total, MAXSEL) : MAXSEL;
        // in-wave fence: sel writes (cross-lane) complete before reads
        __asm__ volatile("s_waitcnt lgkmcnt(0)" ::: "memory");
        const float* qh = qs + h*64;

        if (L <= 64){
            // ---------- register softmax fast path ----------
            int kkey = 0;
            float s = -3.4e38f;
            if (lane < L){
                kkey = sel[wave][lane];
                const uint4* kr = (const uint4*)(Kb + (size_t)kkey*EMBED + h*64);
                float acc = 0.f;
                #pragma unroll
                for (int p=0;p<8;p++){ uint4 u = kr[p]; fma8(qh+p*8, u.x,u.y,u.z,u.w, acc); }
                s = acc * 0.125f;
            }
            float mloc = s;
            #pragma unroll
            for (int off=32; off; off>>=1) mloc = fmaxf(mloc, __shfl_xor(mloc, off, 64));
            float e = (lane < L) ? __expf(s - mloc) : 0.f;
            float ssum = e;
            #pragma unroll
            for (int off=32; off; off>>=1) ssum += __shfl_xor(ssum, off, 64);
            float inv = 1.f / fmaxf(ssum, 1e-37f);
            const u16* vb = Vb + h*64 + lane;
            float acc = 0.f;
            int j = 0;
            for (; j+4<=L; j+=4){
                float e0 = __shfl(e, j,   64), e1 = __shfl(e, j+1, 64);
                float e2 = __shfl(e, j+2, 64), e3 = __shfl(e, j+3, 64);
                int   k0 = __shfl(kkey, j,   64), k1 = __shfl(kkey, j+1, 64);
                int   k2 = __shfl(kkey, j+2, 64), k3 = __shfl(kkey, j+3, 64);
                float v0 = bf2f(vb[(size_t)k0*EMBED]);
                float v1 = bf2f(vb[(size_t)k1*EMBED]);
                float v2 = bf2f(vb[(size_t)k2*EMBED]);
                float v3 = bf2f(vb[(size_t)k3*EMBED]);
                acc += e0*v0; acc += e1*v1; acc += e2*v2; acc += e3*v3;
            }
            for (; j<L; j++){
                float ej = __shfl(e, j, 64);
                int   kj = __shfl(kkey, j, 64);
                acc += ej * bf2f(vb[(size_t)kj*EMBED]);
            }
            float o = acc * inv;
            if (!fq) ((u16*)out)[(size_t)q*EMBED + h*64 + lane] = f2b(o);
            else     ((float*)out)[(size_t)q*EMBED + h*64 + lane] = o;
        } else {
            // ---------- original LDS path (L > 64, incl. fallback 256) ----------
            float mloc = -3.4e38f;
            for (int jj=lane; jj<L; jj+=64){
                int kkey = sel[wave][jj];
                const uint4* kr = (const uint4*)(Kb + (size_t)kkey*EMBED + h*64);
                float acc = 0.f;
                #pragma unroll
                for (int p=0;p<8;p++){ uint4 u = kr[p]; fma8(qh+p*8, u.x,u.y,u.z,u.w, acc); }
                float s = acc * 0.125f;
                sc[wave][jj] = s;
                mloc = fmaxf(mloc, s);
            }
            #pragma unroll
            for (int off=32; off; off>>=1) mloc = fmaxf(mloc, __shfl_xor(mloc, off, 64));
            float ssum = 0.f;
            for (int jj=lane; jj<L; jj+=64){
                float e = __expf(sc[wave][jj] - mloc);
                sc[wave][jj] = e; ssum += e;
            }
            #pragma unroll
            for (int off=32; off; off>>=1) ssum += __shfl_xor(ssum, off, 64);
            float inv = 1.f / fmaxf(ssum, 1e-37f);
            // in-wave fence: sc writes (cross-lane reads below) complete
            __asm__ volatile("s_waitcnt lgkmcnt(0)" ::: "memory");
            float acc = 0.f;
            for (int j=0; j<L; j++){
                int kkey = sel[wave][j];
                acc += sc[wave][j] * bf2f(Vb[(size_t)kkey*EMBED + h*64 + lane]);
            }
            float o = acc * inv;
            if (!fq) ((u16*)out)[(size_t)q*EMBED + h*64 + lane] = f2b(o);
            else     ((float*)out)[(size_t)q*EMBED + h*64 + lane] = o;
        }
    }
}

// ============ K3: output projection, in place on d_out ============
// grid 256: 8 rows/block (best measured variant — round-5/7 bench). W streamed
// global->register (cols t, t+256), X broadcast from LDS.
__global__ __launch_bounds__(256) void oproj_kernel(
    void* __restrict__ out, const void* __restrict__ Wo, const void* __restrict__ bo)
{
    u32 fq = sniffp(out);                 // attn output dtype (== final out dtype)
    u32 fw = sniffp(Wo), fb = sniffp(bo);
    int r0 = blockIdx.x * 8;
    int t = threadIdx.x;
    __shared__ __align__(16) float xst[8*516];   // 16.5 KB

    // stage this block's 8 rows BEFORE any overwrite
    for (int i=t; i<1024; i+=256){
        int row = i>>7, c4 = i&127;
        float4 v;
        if (!fq){
            const u32* xp = (const u32*)((const u16*)out + (size_t)(r0+row)*EMBED);
            u32 a = xp[c4*2], b = xp[c4*2+1];
            v = make_float4(lof(a), hif(a), lof(b), hif(b));
        } else {
            v = ((const float4*)((const float*)out + (size_t)(r0+row)*EMBED))[c4];
        }
        *(float4*)(xst + row*516 + c4*4) = v;
    }
    __syncthreads();

    float acc2[8][2];
    #pragma unroll
    for (int r=0;r<8;r++){ acc2[r][0]=0.f; acc2[r][1]=0.f; }

    if (fw){
        const float* w1 = (const float*)Wo + (size_t)t*EMBED;
        const float* w2 = (const float*)Wo + (size_t)(t+256)*EMBED;
        float4 pa0 = *(const float4*)(w1+ 0), pa1 = *(const float4*)(w1+ 4),
               pa2 = *(const float4*)(w1+ 8), pa3 = *(const float4*)(w1+12);
        float4 pb0 = *(const float4*)(w2+ 0), pb1 = *(const float4*)(w2+ 4),
               pb2 = *(const float4*)(w2+ 8), pb3 = *(const float4*)(w2+12);
        #pragma unroll 1
        for (int k0=0; k0<512; k0+=32){
            float4 qa0 = *(const float4*)(w1+k0+16), qa1 = *(const float4*)(w1+k0+20),
                   qa2 = *(const float4*)(w1+k0+24), qa3 = *(const float4*)(w1+k0+28);
            float4 qb0 = *(const float4*)(w2+k0+16), qb1 = *(const float4*)(w2+k0+20),
                   qb2 = *(const float4*)(w2+k0+24), qb3 = *(const float4*)(w2+k0+28);
            #pragma unroll
            for (int r=0;r<8;r++)
                fma16x2(xst + r*516 + k0, pa0,pa1,pa2,pa3, pb0,pb1,pb2,pb3,
                        acc2[r][0], acc2[r][1]);
            if (k0+32 < 512){
                pa0 = *(const float4*)(w1+k0+32); pa1 = *(const float4*)(w1+k0+36);
                pa2 = *(const float4*)(w1+k0+40); pa3 = *(const float4*)(w1+k0+44);
                pb0 = *(const float4*)(w2+k0+32); pb1 = *(const float4*)(w2+k0+36);
                pb2 = *(const float4*)(w2+k0+40); pb3 = *(const float4*)(w2+k0+44);
            }
            #pragma unroll
            for (int r=0;r<8;r++)
                fma16x2(xst + r*516 + k0+16, qa0,qa1,qa2,qa3, qb0,qb1,qb2,qb3,
                        acc2[r][0], acc2[r][1]);
        }
    } else {
        const uint4* w1 = (const uint4*)((const u16*)Wo + (size_t)t*EMBED);
        const uint4* w2 = (const uint4*)((const u16*)Wo + (size_t)(t+256)*EMBED);
        uint4 pa0 = w1[0], pa1 = w1[1], pb0 = w2[0], pb1 = w2[1];
        #pragma unroll 1
        for (int k0=0; k0<512; k0+=32){
            int u = k0>>3;
            uint4 qa0 = w1[u+2], qa1 = w1[u+3], qb0 = w2[u+2], qb1 = w2[u+3];
            float4 a0,a1,a2,a3,b0,b1,b2,b3;
            ub2(pa0,a0,a1); ub2(pa1,a2,a3); ub2(pb0,b0,b1); ub2(pb1,b2,b3);
            #pragma unroll
            for (int r=0;r<8;r++)
                fma16x2(xst + r*516 + k0, a0,a1,a2,a3, b0,b1,b2,b3,
                        acc2[r][0], acc2[r][1]);
            if (k0+32 < 512){ pa0 = w1[u+4]; pa1 = w1[u+5]; pb0 = w2[u+4]; pb1 = w2[u+5]; }
            ub2(qa0,a0,a1); ub2(qa1,a2,a3); ub2(qb0,b0,b1); ub2(qb1,b2,b3);
            #pragma unroll
            for (int r=0;r<8;r++)
                fma16x2(xst + r*516 + k0+16, a0,a1,a2,a3, b0,b1,b2,b3,
                        acc2[r][0], acc2[r][1]);
        }
    }
    float b0 = fb ? ((const float*)bo)[t]     : bf2f(((const u16*)bo)[t]);
    float b1 = fb ? ((const float*)bo)[t+256] : bf2f(((const u16*)bo)[t+256]);
    if (!fq){
        u16* o = (u16*)out;
        #pragma unroll
        for (int r=0;r<8;r++){
            o[(size_t)(r0+r)*EMBED + t]       = f2b(acc2[r][0]+b0);
            o[(size_t)(r0+r)*EMBED + t + 256] = f2b(acc2[r][1]+b1);
        }
    } else {
        float* o = (float*)out;
        #pragma unroll
        for (int r=0;r<8;r++){
            o[(size_t)(r0+r)*EMBED + t]       = acc2[r][0]+b0;
            o[(size_t)(r0+r)*EMBED + t + 256] = acc2[r][1]+b1;
        }
    }
}

extern "C" void kernel_launch(void* const* d_in, const int* in_sizes, int n_in,
                              void* d_out, int out_size, void* d_ws, size_t ws_size,
                              hipStream_t stream)
{
    const void* query = d_in[0];
    const void* key   = d_in[1];
    const void* value = d_in[2];
    const void* Wq = d_in[3];
    const void* bq = d_in[4];
    const void* Wk = d_in[5];
    const void* bk = d_in[6];
    const void* Wv = d_in[7];
    const void* bv = d_in[8];
    const void* Wo = d_in[9];
    const void* bo = d_in[10];
    const void* cen = d_in[11];

    // ws layout:
    //   [0, 32K)        qbin u16[16384]
    //   [32K, 64K)      kbin u16[16384]
    //   [64K, 64K+2M)   Kb bf16 (normalized)
    //   [64K+2M, +2M)   Vb bf16 (raw)
    char* ws = (char*)d_ws;
    u16* qbin = (u16*)ws;
    u16* kbin = (u16*)(ws + 32768);
    u16* Kb   = (u16*)(ws + 65536);
    u16* Vb   = (u16*)(ws + 65536 + (size_t)2*1024*1024);

    projqkv_kernel<<<dim3(256,3), 256, 0, stream>>>(query,key,value,Wq,bq,Wk,bk,Wv,bv,cen,
                                                    d_out,Kb,Vb,qbin,kbin);
    attn_kernel<<<2048, 256, 0, stream>>>(query,Kb,Vb,qbin,kbin,d_out);
    oproj_kernel<<<256, 256, 0, stream>>>(d_out,Wo,bo);
}

// Round 11
// 276.246 us; speedup vs baseline: 1.0663x; 1.0663x over previous
//
#include <hip/hip_runtime.h>
#include <hip/hip_bf16.h>

#define NTOK 2048
#define EMBED 512
#define NHEADS 8
#define HD 64
#define NBINS 512
#define MAXSEL 256

typedef unsigned short u16;
typedef unsigned int u32;

__device__ __forceinline__ float lof(u32 u){ return __uint_as_float(u << 16); }
__device__ __forceinline__ float hif(u32 u){ return __uint_as_float(u & 0xffff0000u); }
__device__ __forceinline__ float bf2f(u16 u){ return __uint_as_float(((u32)u) << 16); }
__device__ __forceinline__ u16 f2b(float f){
    __hip_bfloat16 h = __float2bfloat16(f);
    return *(u16*)&h;
}
__device__ __forceinline__ u32 pack2(float lo, float hi){
    return (u32)f2b(lo) | ((u32)f2b(hi) << 16);
}
__device__ __forceinline__ void fma8(const float* x, u32 ux, u32 uy, u32 uz, u32 uw, float& a){
    a += x[0]*lof(ux) + x[1]*hif(ux) + x[2]*lof(uy) + x[3]*hif(uy)
       + x[4]*lof(uz) + x[5]*hif(uz) + x[6]*lof(uw) + x[7]*hif(uw);
}

// Inline per-block dtype sniff: read 64 even u16s of the tensor as bf16.
// f32 data -> low mantissa halves -> random bf16 exponents -> max>100 w.p. ~1.
// bf16 data here (|x|<6) -> max<10. All threads same samples -> uniform branch.
__device__ __forceinline__ u32 sniffp(const void* p){
    const u16* s = (const u16*)p;
    float m = 0.f;
    #pragma unroll
    for (int k=0; k<64; k++) m = fmaxf(m, fabsf(bf2f(s[2*k])));
    return (m > 100.f) ? 1u : 0u;
}

// unpack 8 bf16 (uint4) -> 2x float4
__device__ __forceinline__ void ub2(const uint4& u, float4& f0, float4& f1){
    f0 = make_float4(lof(u.x), hif(u.x), lof(u.y), hif(u.y));
    f1 = make_float4(lof(u.z), hif(u.z), lof(u.w), hif(u.w));
}

// 16-k dot step for two output columns sharing one X broadcast read.
// xp: LDS broadcast (uniform addr across wave) — 4x ds_read_b128.
// a0..a3 / b0..b3: W[colA][k..k+16), W[colB][k..k+16) in registers.
__device__ __forceinline__ void fma16x2(const float* xp,
    const float4& a0, const float4& a1, const float4& a2, const float4& a3,
    const float4& b0, const float4& b1, const float4& b2, const float4& b3,
    float& A, float& B)
{
    float4 x0 = *(const float4*)(xp);
    float4 x1 = *(const float4*)(xp+4);
    float4 x2 = *(const float4*)(xp+8);
    float4 x3 = *(const float4*)(xp+12);
    A += x0.x*a0.x; A += x0.y*a0.y; A += x0.z*a0.z; A += x0.w*a0.w;
    A += x1.x*a1.x; A += x1.y*a1.y; A += x1.z*a1.z; A += x1.w*a1.w;
    A += x2.x*a2.x; A += x2.y*a2.y; A += x2.z*a2.z; A += x2.w*a2.w;
    A += x3.x*a3.x; A += x3.y*a3.y; A += x3.z*a3.z; A += x3.w*a3.w;
    B += x0.x*b0.x; B += x0.y*b0.y; B += x0.z*b0.z; B += x0.w*b0.w;
    B += x1.x*b1.x; B += x1.y*b1.y; B += x1.z*b1.z; B += x1.w*b1.w;
    B += x2.x*b2.x; B += x2.y*b2.y; B += x2.z*b2.z; B += x2.w*b2.w;
    B += x3.x*b3.x; B += x3.y*b3.y; B += x3.z*b3.z; B += x3.w*b3.w;
}

// ============ K1: QKV projection + per-head norm + centroid bins ============
// grid (256, 3): 8 tokens/block, y: 0=Q 1=K 2=V. block 256 (4 waves).
// GEMM: ROUND-1 VERIFIED (6 restructures all lost — do not touch): X-tile
// broadcast from LDS; W streamed GLOBAL->REGISTER (cols t, t+256) with 16-k
// ping-pong prefetch. Scan v8 (round-9 verified): ps stride 68, b128 row
// reads. v11: ubuf shrunk 4608->4352 floats (actual scan-tile footprint)
// -> total LDS 40192B <= 40960 -> 4 blocks/CU instead of 3 (+33% waves).
__global__ __launch_bounds__(256) void projqkv_kernel(
    const void* __restrict__ Xq, const void* __restrict__ Xk, const void* __restrict__ Xv,
    const void* __restrict__ Wq, const void* __restrict__ bq,
    const void* __restrict__ Wk, const void* __restrict__ bk,
    const void* __restrict__ Wv, const void* __restrict__ bv,
    const void* __restrict__ cen,
    void* __restrict__ outQ,                 // d_out: normalized Q staging (out dtype)
    u16* __restrict__ Kb, u16* __restrict__ Vb,
    u16* __restrict__ qbin, u16* __restrict__ kbin)
{
    int which = blockIdx.y;
    const void *X, *W, *Bb;
    if (which==0){ X=Xq; W=Wq; Bb=bq; }
    else if (which==1){ X=Xk; W=Wk; Bb=bk; }
    else { X=Xv; W=Wv; Bb=bv; }
    u32 fx = sniffp(X), fw = sniffp(W), fb = sniffp(Bb);
    int r0 = blockIdx.x * 8;
    int t = threadIdx.x;

    __shared__ __align__(16) float ubuf[4352];  // scan cent tiles [dim 64][68] (max idx 4347)
    __shared__ __align__(16) float ps[64*68];   // results [(tok*8+head)][68]; first 4128
                                                // floats alias X-stage [8][516] during GEMM
    __shared__ float nrm2[64][4];
    __shared__ float invn[64];
    __shared__ float bvl[64][8];
    __shared__ int   bil[64][8];

    float* xstage = ps;
    // Phase A: stage X tile (8 x 512), coalesced 16B/lane
    for (int i=t; i<1024; i+=256){
        int row = i>>7, c4 = i&127;
        float4 v;
        if (!fx){
            const u32* xp = (const u32*)((const u16*)X + (size_t)(r0+row)*EMBED);
            u32 a = xp[c4*2], b = xp[c4*2+1];
            v = make_float4(lof(a), hif(a), lof(b), hif(b));
        } else {
            v = ((const float4*)((const float*)X + (size_t)(r0+row)*EMBED))[c4];
        }
        *(float4*)(xstage + row*516 + c4*4) = v;
    }
    __syncthreads();                     // xstage ready

    float acc2[8][2];
    #pragma unroll
    for (int r=0;r<8;r++){ acc2[r][0]=0.f; acc2[r][1]=0.f; }

    if (fw){
        const float* w1 = (const float*)W + (size_t)t*EMBED;
        const float* w2 = (const float*)W + (size_t)(t+256)*EMBED;
        float4 pa0 = *(const float4*)(w1+ 0), pa1 = *(const float4*)(w1+ 4),
               pa2 = *(const float4*)(w1+ 8), pa3 = *(const float4*)(w1+12);
        float4 pb0 = *(const float4*)(w2+ 0), pb1 = *(const float4*)(w2+ 4),
               pb2 = *(const float4*)(w2+ 8), pb3 = *(const float4*)(w2+12);
        #pragma unroll 1
        for (int k0=0; k0<512; k0+=32){
            float4 qa0 = *(const float4*)(w1+k0+16), qa1 = *(const float4*)(w1+k0+20),
                   qa2 = *(const float4*)(w1+k0+24), qa3 = *(const float4*)(w1+k0+28);
            float4 qb0 = *(const float4*)(w2+k0+16), qb1 = *(const float4*)(w2+k0+20),
                   qb2 = *(const float4*)(w2+k0+24), qb3 = *(const float4*)(w2+k0+28);
            #pragma unroll
            for (int r=0;r<8;r++)
                fma16x2(xstage + r*516 + k0, pa0,pa1,pa2,pa3, pb0,pb1,pb2,pb3,
                        acc2[r][0], acc2[r][1]);
            if (k0+32 < 512){
                pa0 = *(const float4*)(w1+k0+32); pa1 = *(const float4*)(w1+k0+36);
                pa2 = *(const float4*)(w1+k0+40); pa3 = *(const float4*)(w1+k0+44);
                pb0 = *(const float4*)(w2+k0+32); pb1 = *(const float4*)(w2+k0+36);
                pb2 = *(const float4*)(w2+k0+40); pb3 = *(const float4*)(w2+k0+44);
            }
            #pragma unroll
            for (int r=0;r<8;r++)
                fma16x2(xstage + r*516 + k0+16, qa0,qa1,qa2,qa3, qb0,qb1,qb2,qb3,
                        acc2[r][0], acc2[r][1]);
        }
    } else {
        const uint4* w1 = (const uint4*)((const u16*)W + (size_t)t*EMBED);
        const uint4* w2 = (const uint4*)((const u16*)W + (size_t)(t+256)*EMBED);
        uint4 pa0 = w1[0], pa1 = w1[1], pb0 = w2[0], pb1 = w2[1];
        #pragma unroll 1
        for (int k0=0; k0<512; k0+=32){
            int u = k0>>3;
            uint4 qa0 = w1[u+2], qa1 = w1[u+3], qb0 = w2[u+2], qb1 = w2[u+3];
            float4 a0,a1,a2,a3,b0,b1,b2,b3;
            ub2(pa0,a0,a1); ub2(pa1,a2,a3); ub2(pb0,b0,b1); ub2(pb1,b2,b3);
            #pragma unroll
            for (int r=0;r<8;r++)
                fma16x2(xstage + r*516 + k0, a0,a1,a2,a3, b0,b1,b2,b3,
                        acc2[r][0], acc2[r][1]);
            if (k0+32 < 512){ pa0 = w1[u+4]; pa1 = w1[u+5]; pb0 = w2[u+4]; pb1 = w2[u+5]; }
            ub2(qa0,a0,a1); ub2(qa1,a2,a3); ub2(qb0,b0,b1); ub2(qb1,b2,b3);
            #pragma unroll
            for (int r=0;r<8;r++)
                fma16x2(xstage + r*516 + k0+16, a0,a1,a2,a3, b0,b1,b2,b3,
                        acc2[r][0], acc2[r][1]);
        }
    }
    __syncthreads();                     // all xstage reads done before ps overwrite
    {
        float b0 = fb ? ((const float*)Bb)[t]     : bf2f(((const u16*)Bb)[t]);
        float b1 = fb ? ((const float*)Bb)[t+256] : bf2f(((const u16*)Bb)[t+256]);
        int h0 = t>>6, c0 = t&63, h1 = (t+256)>>6, c1 = (t+256)&63;
        #pragma unroll
        for (int r=0;r<8;r++){
            ps[(r*8+h0)*68 + c0] = acc2[r][0]+b0;
            ps[(r*8+h1)*68 + c1] = acc2[r][1]+b1;
        }
    }
    __syncthreads();

    if (which == 2){
        // V: store raw bf16, 16 elems/thread
        int hr = t>>2, q4 = t&3;
        int row = hr>>3, head = hr&7;
        const float* src = ps + hr*68 + q4*16;
        u16* dst = Vb + (size_t)(r0+row)*EMBED + head*64 + q4*16;
        #pragma unroll
        for (int j8=0;j8<2;j8++){
            uint4 v;
            v.x = pack2(src[j8*8+0],src[j8*8+1]); v.y = pack2(src[j8*8+2],src[j8*8+3]);
            v.z = pack2(src[j8*8+4],src[j8*8+5]); v.w = pack2(src[j8*8+6],src[j8*8+7]);
            ((uint4*)dst)[j8] = v;
        }
        return;
    }

    // ---------- centroid scan: register-tiled LDS GEMM + argmax, tile prefetch ----------
    u32 fc = sniffp(cen);
    int rg = t>>3, cg = t&7;             // rows {2rg, 2rg+1}, cents cg*8..cg*8+7 per tile
    float best[2] = {-3.4e38f,-3.4e38f};
    int   bidx[2] = {0,0};
    float cpre[16];
    #pragma unroll
    for (int it=0; it<16; it++){
        int e = t + it*256, j = e>>6, k = e&63;
        cpre[it] = fc ? ((const float*)cen)[(size_t)j*HD + k]
                      : bf2f(((const u16*)cen)[(size_t)j*HD + k]);
    }
    for (int tt=0; tt<8; tt++){
        __syncthreads();                 // prev tile consumed (tt=0: ubuf free post-GEMM)
        #pragma unroll
        for (int it=0; it<16; it++){
            int e = t + it*256, j = e>>6, k = e&63;
            ubuf[k*68 + j] = cpre[it];
        }
        if (tt < 7){
            #pragma unroll
            for (int it=0; it<16; it++){
                int e = t + it*256, j = e>>6, k = e&63;
                int gj = (tt+1)*64 + j;
                cpre[it] = fc ? ((const float*)cen)[(size_t)gj*HD + k]
                              : bf2f(((const u16*)cen)[(size_t)gj*HD + k]);
            }
        }
        __syncthreads();
        float acc[2][8];
        #pragma unroll
        for (int j=0;j<2;j++)
            #pragma unroll
            for (int c=0;c<8;c++) acc[j][c]=0.f;
        const float* pr0 = ps + (2*rg)*68;
        const float* pr1 = pr0 + 68;
        #pragma unroll 1
        for (int k4=0;k4<64;k4+=4){
            float4 ra = *(const float4*)(pr0 + k4);     // b128 row reads
            float4 rb = *(const float4*)(pr1 + k4);
            const float* cbase = ubuf + k4*68 + cg*8;
            #define SCANK(OFF, AX, BX) { \
                const float4* cp = (const float4*)(cbase + (OFF)); \
                float4 c0 = cp[0], c1 = cp[1]; \
                acc[0][0]+=(AX)*c0.x; acc[0][1]+=(AX)*c0.y; acc[0][2]+=(AX)*c0.z; acc[0][3]+=(AX)*c0.w; \
                acc[0][4]+=(AX)*c1.x; acc[0][5]+=(AX)*c1.y; acc[0][6]+=(AX)*c1.z; acc[0][7]+=(AX)*c1.w; \
                acc[1][0]+=(BX)*c0.x; acc[1][1]+=(BX)*c0.y; acc[1][2]+=(BX)*c0.z; acc[1][3]+=(BX)*c0.w; \
                acc[1][4]+=(BX)*c1.x; acc[1][5]+=(BX)*c1.y; acc[1][6]+=(BX)*c1.z; acc[1][7]+=(BX)*c1.w; }
            SCANK(0,   ra.x, rb.x)
            SCANK(68,  ra.y, rb.y)
            SCANK(136, ra.z, rb.z)
            SCANK(204, ra.w, rb.w)
            #undef SCANK
        }
        #pragma unroll
        for (int j=0;j<2;j++){
            #pragma unroll
            for (int c=0;c<8;c++){
                int gi = tt*64 + cg*8 + c;   // ascending in-thread -> strict > keeps first
                if (acc[j][c] > best[j]){ best[j]=acc[j][c]; bidx[j]=gi; }
            }
        }
    }
    bvl[2*rg  ][cg]=best[0]; bil[2*rg  ][cg]=bidx[0];
    bvl[2*rg+1][cg]=best[1]; bil[2*rg+1][cg]=bidx[1];
    {
        int hr = t>>2, q4 = t&3;
        const float* src = ps + hr*68 + q4*16;
        float ss=0.f;
        #pragma unroll
        for (int d=0;d<16;d++) ss += src[d]*src[d];
        nrm2[hr][q4]=ss;
    }
    __syncthreads();
    if (t < 64){
        int hr = t;
        invn[hr] = 1.f / fmaxf(sqrtf(nrm2[hr][0]+nrm2[hr][1]+nrm2[hr][2]+nrm2[hr][3]), 1e-12f);
        float bv = bvl[hr][0]; int bi = bil[hr][0];
        #pragma unroll
        for (int g=1; g<8; g++){         // disjoint index sets: (>, ==&&<) merge = np.argmax
            float ov = bvl[hr][g]; int oi = bil[hr][g];
            if (ov > bv || (ov == bv && oi < bi)){ bv = ov; bi = oi; }
        }
        u16* bins = (which==0) ? qbin : kbin;
        int token = r0 + (hr>>3), head = hr&7;
        bins[head*NTOK + token] = (u16)bi;
    }
    __syncthreads();
    {
        int hr = t>>2, q4 = t&3;
        float inv = invn[hr];
        const float* src = ps + hr*68 + q4*16;
        int row = hr>>3, head = hr&7;
        size_t off = (size_t)(r0+row)*EMBED + head*64 + q4*16;
        if (which == 1){
            u16* dst = Kb + off;
            #pragma unroll
            for (int j8=0;j8<2;j8++){
                uint4 v;
                v.x = pack2(src[j8*8+0]*inv, src[j8*8+1]*inv);
                v.y = pack2(src[j8*8+2]*inv, src[j8*8+3]*inv);
                v.z = pack2(src[j8*8+4]*inv, src[j8*8+5]*inv);
                v.w = pack2(src[j8*8+6]*inv, src[j8*8+7]*inv);
                ((uint4*)dst)[j8] = v;
            }
        } else if (!fx){
            u16* dst = (u16*)outQ + off;
            #pragma unroll
            for (int j8=0;j8<2;j8++){
                uint4 v;
                v.x = pack2(src[j8*8+0]*inv, src[j8*8+1]*inv);
                v.y = pack2(src[j8*8+2]*inv, src[j8*8+3]*inv);
                v.z = pack2(src[j8*8+4]*inv, src[j8*8+5]*inv);
                v.w = pack2(src[j8*8+6]*inv, src[j8*8+7]*inv);
                ((uint4*)dst)[j8] = v;
            }
        } else {
            float* dst = (float*)outQ + off;
            #pragma unroll
            for (int j4=0;j4<4;j4++){
                float4 v = make_float4(src[j4*4+0]*inv, src[j4*4+1]*inv,
                                       src[j4*4+2]*inv, src[j4*4+3]*inv);
                ((float4*)dst)[j4] = v;
            }
        }
    }
}

// ============ K2: attention ============
// grid 2048 (one block per query token), 4 waves x 2 heads. Qb read from d_out row q,
// AO written back to the same row (race-free).
// v2 (round-8 verified): sel/sc wave-local -> no block barriers after qs;
// register-softmax fast path for L<=64 (typical L ~ Poisson(12)); LDS slow
// path for L>64 / fallback.
__global__ __launch_bounds__(256) void attn_kernel(
    const void* __restrict__ query,
    const u16* __restrict__ Kb, const u16* __restrict__ Vb,
    const u16* __restrict__ qbin, const u16* __restrict__ kbin,
    void* __restrict__ out)
{
    u32 fq = sniffp(query);
    int q = blockIdx.x, t = threadIdx.x;
    int wave = t>>6, lane = t&63;
    __shared__ float qs[512];
    __shared__ float sc[4][256];
    __shared__ u16   sel[4][256];

    if (!fq){
        u32 u = ((const u32*)out)[(size_t)q*256 + t];
        qs[2*t] = lof(u); qs[2*t+1] = hif(u);
    } else {
        float2 f = ((const float2*)out)[(size_t)q*256 + t];
        qs[2*t] = f.x; qs[2*t+1] = f.y;
    }
    __syncthreads();                 // qs ready (only block-wide dependency)

    for (int hh=0; hh<2; hh++){
        int h = wave*2 + hh;
        int myqb = qbin[h*NTOK + q];
        const uint4* kbp = (const uint4*)(kbin + h*NTOK + lane*32);
        u32 fl = 0;
        #pragma unroll
        for (int w4=0; w4<4; w4++){
            uint4 kw = kbp[w4];
            u32 arr[4] = {kw.x, kw.y, kw.z, kw.w};
            #pragma unroll
            for (int e=0;e<4;e++){
                int b0 = (int)(arr[e] & 0xffff), b1 = (int)(arr[e] >> 16);
                int d0 = (myqb - b0) & (NBINS-1), d1 = (myqb - b1) & (NBINS-1);
                if (d0 <= 1 || d0 >= NBINS-1) fl |= 1u << (w4*8 + e*2);
                if (d1 <= 1 || d1 >= NBINS-1) fl |= 1u << (w4*8 + e*2 + 1);
            }
        }
        int cnt = __popc(fl);
        int sum = cnt;
        #pragma unroll
        for (int off=1; off<64; off<<=1){
            int v = __shfl_up(sum, off, 64);
            if (lane >= off) sum += v;
        }
        int total = __shfl(sum, 63, 64);
        int r = sum - cnt;
        if (total){
            u32 f2 = fl;
            while (f2){
                int j = __ffs(f2) - 1; f2 &= f2 - 1;
                if (r < MAXSEL) sel[wave][r] = (u16)(lane*32 + j);
                r++;
            }
        } else {
            #pragma unroll
            for (int kq=0;kq<4;kq++) sel[wave][lane*4+kq] = (u16)(lane*4+kq);
        }
        int L = total ? min(total, MAXSEL) : MAXSEL;
        // in-wave fence: sel writes (cross-lane) complete before reads
        __asm__ volatile("s_waitcnt lgkmcnt(0)" ::: "memory");
        const float* qh = qs + h*64;

        if (L <= 64){
            // ---------- register softmax fast path ----------
            int kkey = 0;
            float s = -3.4e38f;
            if (lane < L){
                kkey = sel[wave][lane];
                const uint4* kr = (const uint4*)(Kb + (size_t)kkey*EMBED + h*64);
                float acc = 0.f;
                #pragma unroll
                for (int p=0;p<8;p++){ uint4 u = kr[p]; fma8(qh+p*8, u.x,u.y,u.z,u.w, acc); }
                s = acc * 0.125f;
            }
            float mloc = s;
            #pragma unroll
            for (int off=32; off; off>>=1) mloc = fmaxf(mloc, __shfl_xor(mloc, off, 64));
            float e = (lane < L) ? __expf(s - mloc) : 0.f;
            float ssum = e;
            #pragma unroll
            for (int off=32; off; off>>=1) ssum += __shfl_xor(ssum, off, 64);
            float inv = 1.f / fmaxf(ssum, 1e-37f);
            const u16* vb = Vb + h*64 + lane;
            float acc = 0.f;
            int j = 0;
            for (; j+4<=L; j+=4){
                float e0 = __shfl(e, j,   64), e1 = __shfl(e, j+1, 64);
                float e2 = __shfl(e, j+2, 64), e3 = __shfl(e, j+3, 64);
                int   k0 = __shfl(kkey, j,   64), k1 = __shfl(kkey, j+1, 64);
                int   k2 = __shfl(kkey, j+2, 64), k3 = __shfl(kkey, j+3, 64);
                float v0 = bf2f(vb[(size_t)k0*EMBED]);
                float v1 = bf2f(vb[(size_t)k1*EMBED]);
                float v2 = bf2f(vb[(size_t)k2*EMBED]);
                float v3 = bf2f(vb[(size_t)k3*EMBED]);
                acc += e0*v0; acc += e1*v1; acc += e2*v2; acc += e3*v3;
            }
            for (; j<L; j++){
                float ej = __shfl(e, j, 64);
                int   kj = __shfl(kkey, j, 64);
                acc += ej * bf2f(vb[(size_t)kj*EMBED]);
            }
            float o = acc * inv;
            if (!fq) ((u16*)out)[(size_t)q*EMBED + h*64 + lane] = f2b(o);
            else     ((float*)out)[(size_t)q*EMBED + h*64 + lane] = o;
        } else {
            // ---------- original LDS path (L > 64, incl. fallback 256) ----------
            float mloc = -3.4e38f;
            for (int jj=lane; jj<L; jj+=64){
                int kkey = sel[wave][jj];
                const uint4* kr = (const uint4*)(Kb + (size_t)kkey*EMBED + h*64);
                float acc = 0.f;
                #pragma unroll
                for (int p=0;p<8;p++){ uint4 u = kr[p]; fma8(qh+p*8, u.x,u.y,u.z,u.w, acc); }
                float s = acc * 0.125f;
                sc[wave][jj] = s;
                mloc = fmaxf(mloc, s);
            }
            #pragma unroll
            for (int off=32; off; off>>=1) mloc = fmaxf(mloc, __shfl_xor(mloc, off, 64));
            float ssum = 0.f;
            for (int jj=lane; jj<L; jj+=64){
                float e = __expf(sc[wave][jj] - mloc);
                sc[wave][jj] = e; ssum += e;
            }
            #pragma unroll
            for (int off=32; off; off>>=1) ssum += __shfl_xor(ssum, off, 64);
            float inv = 1.f / fmaxf(ssum, 1e-37f);
            // in-wave fence: sc writes (cross-lane reads below) complete
            __asm__ volatile("s_waitcnt lgkmcnt(0)" ::: "memory");
            float acc = 0.f;
            for (int j=0; j<L; j++){
                int kkey = sel[wave][j];
                acc += sc[wave][j] * bf2f(Vb[(size_t)kkey*EMBED + h*64 + lane]);
            }
            float o = acc * inv;
            if (!fq) ((u16*)out)[(size_t)q*EMBED + h*64 + lane] = f2b(o);
            else     ((float*)out)[(size_t)q*EMBED + h*64 + lane] = o;
        }
    }
}

// ============ K3: output projection, in place on d_out ============
// grid 256: 8 rows/block (best measured variant — round-5/7 bench). W streamed
// global->register (cols t, t+256), X broadcast from LDS.
__global__ __launch_bounds__(256) void oproj_kernel(
    void* __restrict__ out, const void* __restrict__ Wo, const void* __restrict__ bo)
{
    u32 fq = sniffp(out);                 // attn output dtype (== final out dtype)
    u32 fw = sniffp(Wo), fb = sniffp(bo);
    int r0 = blockIdx.x * 8;
    int t = threadIdx.x;
    __shared__ __align__(16) float xst[8*516];   // 16.5 KB

    // stage this block's 8 rows BEFORE any overwrite
    for (int i=t; i<1024; i+=256){
        int row = i>>7, c4 = i&127;
        float4 v;
        if (!fq){
            const u32* xp = (const u32*)((const u16*)out + (size_t)(r0+row)*EMBED);
            u32 a = xp[c4*2], b = xp[c4*2+1];
            v = make_float4(lof(a), hif(a), lof(b), hif(b));
        } else {
            v = ((const float4*)((const float*)out + (size_t)(r0+row)*EMBED))[c4];
        }
        *(float4*)(xst + row*516 + c4*4) = v;
    }
    __syncthreads();

    float acc2[8][2];
    #pragma unroll
    for (int r=0;r<8;r++){ acc2[r][0]=0.f; acc2[r][1]=0.f; }

    if (fw){
        const float* w1 = (const float*)Wo + (size_t)t*EMBED;
        const float* w2 = (const float*)Wo + (size_t)(t+256)*EMBED;
        float4 pa0 = *(const float4*)(w1+ 0), pa1 = *(const float4*)(w1+ 4),
               pa2 = *(const float4*)(w1+ 8), pa3 = *(const float4*)(w1+12);
        float4 pb0 = *(const float4*)(w2+ 0), pb1 = *(const float4*)(w2+ 4),
               pb2 = *(const float4*)(w2+ 8), pb3 = *(const float4*)(w2+12);
        #pragma unroll 1
        for (int k0=0; k0<512; k0+=32){
            float4 qa0 = *(const float4*)(w1+k0+16), qa1 = *(const float4*)(w1+k0+20),
                   qa2 = *(const float4*)(w1+k0+24), qa3 = *(const float4*)(w1+k0+28);
            float4 qb0 = *(const float4*)(w2+k0+16), qb1 = *(const float4*)(w2+k0+20),
                   qb2 = *(const float4*)(w2+k0+24), qb3 = *(const float4*)(w2+k0+28);
            #pragma unroll
            for (int r=0;r<8;r++)
                fma16x2(xst + r*516 + k0, pa0,pa1,pa2,pa3, pb0,pb1,pb2,pb3,
                        acc2[r][0], acc2[r][1]);
            if (k0+32 < 512){
                pa0 = *(const float4*)(w1+k0+32); pa1 = *(const float4*)(w1+k0+36);
                pa2 = *(const float4*)(w1+k0+40); pa3 = *(const float4*)(w1+k0+44);
                pb0 = *(const float4*)(w2+k0+32); pb1 = *(const float4*)(w2+k0+36);
                pb2 = *(const float4*)(w2+k0+40); pb3 = *(const float4*)(w2+k0+44);
            }
            #pragma unroll
            for (int r=0;r<8;r++)
                fma16x2(xst + r*516 + k0+16, qa0,qa1,qa2,qa3, qb0,qb1,qb2,qb3,
                        acc2[r][0], acc2[r][1]);
        }
    } else {
        const uint4* w1 = (const uint4*)((const u16*)Wo + (size_t)t*EMBED);
        const uint4* w2 = (const uint4*)((const u16*)Wo + (size_t)(t+256)*EMBED);
        uint4 pa0 = w1[0], pa1 = w1[1], pb0 = w2[0], pb1 = w2[1];
        #pragma unroll 1
        for (int k0=0; k0<512; k0+=32){
            int u = k0>>3;
            uint4 qa0 = w1[u+2], qa1 = w1[u+3], qb0 = w2[u+2], qb1 = w2[u+3];
            float4 a0,a1,a2,a3,b0,b1,b2,b3;
            ub2(pa0,a0,a1); ub2(pa1,a2,a3); ub2(pb0,b0,b1); ub2(pb1,b2,b3);
            #pragma unroll
            for (int r=0;r<8;r++)
                fma16x2(xst + r*516 + k0, a0,a1,a2,a3, b0,b1,b2,b3,
                        acc2[r][0], acc2[r][1]);
            if (k0+32 < 512){ pa0 = w1[u+4]; pa1 = w1[u+5]; pb0 = w2[u+4]; pb1 = w2[u+5]; }
            ub2(qa0,a0,a1); ub2(qa1,a2,a3); ub2(qb0,b0,b1); ub2(qb1,b2,b3);
            #pragma unroll
            for (int r=0;r<8;r++)
                fma16x2(xst + r*516 + k0+16, a0,a1,a2,a3, b0,b1,b2,b3,
                        acc2[r][0], acc2[r][1]);
        }
    }
    float b0 = fb ? ((const float*)bo)[t]     : bf2f(((const u16*)bo)[t]);
    float b1 = fb ? ((const float*)bo)[t+256] : bf2f(((const u16*)bo)[t+256]);
    if (!fq){
        u16* o = (u16*)out;
        #pragma unroll
        for (int r=0;r<8;r++){
            o[(size_t)(r0+r)*EMBED + t]       = f2b(acc2[r][0]+b0);
            o[(size_t)(r0+r)*EMBED + t + 256] = f2b(acc2[r][1]+b1);
        }
    } else {
        float* o = (float*)out;
        #pragma unroll
        for (int r=0;r<8;r++){
            o[(size_t)(r0+r)*EMBED + t]       = acc2[r][0]+b0;
            o[(size_t)(r0+r)*EMBED + t + 256] = acc2[r][1]+b1;
        }
    }
}

extern "C" void kernel_launch(void* const* d_in, const int* in_sizes, int n_in,
                              void* d_out, int out_size, void* d_ws, size_t ws_size,
                              hipStream_t stream)
{
    const void* query = d_in[0];
    const void* key   = d_in[1];
    const void* value = d_in[2];
    const void* Wq = d_in[3];
    const void* bq = d_in[4];
    const void* Wk = d_in[5];
    const void* bk = d_in[6];
    const void* Wv = d_in[7];
    const void* bv = d_in[8];
    const void* Wo = d_in[9];
    const void* bo = d_in[10];
    const void* cen = d_in[11];

    // ws layout:
    //   [0, 32K)        qbin u16[16384]
    //   [32K, 64K)      kbin u16[16384]
    //   [64K, 64K+2M)   Kb bf16 (normalized)
    //   [64K+2M, +2M)   Vb bf16 (raw)
    char* ws = (char*)d_ws;
    u16* qbin = (u16*)ws;
    u16* kbin = (u16*)(ws + 32768);
    u16* Kb   = (u16*)(ws + 65536);
    u16* Vb   = (u16*)(ws + 65536 + (size_t)2*1024*1024);

    projqkv_kernel<<<dim3(256,3), 256, 0, stream>>>(query,key,value,Wq,bq,Wk,bk,Wv,bv,cen,
                                                    d_out,Kb,Vb,qbin,kbin);
    attn_kernel<<<2048, 256, 0, stream>>>(query,Kb,Vb,qbin,kbin,d_out);
    oproj_kernel<<<256, 256, 0, stream>>>(d_out,Wo,bo);
}

// Round 13
// 274.092 us; speedup vs baseline: 1.0747x; 1.0079x over previous
//
#include <hip/hip_runtime.h>
#include <hip/hip_bf16.h>

#define NTOK 2048
#define EMBED 512
#define NHEADS 8
#define HD 64
#define NBINS 512
#define MAXSEL 256

typedef unsigned short u16;
typedef unsigned int u32;

__device__ __forceinline__ float lof(u32 u){ return __uint_as_float(u << 16); }
__device__ __forceinline__ float hif(u32 u){ return __uint_as_float(u & 0xffff0000u); }
__device__ __forceinline__ float bf2f(u16 u){ return __uint_as_float(((u32)u) << 16); }
__device__ __forceinline__ u16 f2b(float f){
    __hip_bfloat16 h = __float2bfloat16(f);
    return *(u16*)&h;
}
__device__ __forceinline__ u32 pack2(float lo, float hi){
    return (u32)f2b(lo) | ((u32)f2b(hi) << 16);
}
__device__ __forceinline__ void fma8(const float* x, u32 ux, u32 uy, u32 uz, u32 uw, float& a){
    a += x[0]*lof(ux) + x[1]*hif(ux) + x[2]*lof(uy) + x[3]*hif(uy)
       + x[4]*lof(uz) + x[5]*hif(uz) + x[6]*lof(uw) + x[7]*hif(uw);
}

// Inline per-block dtype sniff: read 64 even u16s of the tensor as bf16.
// f32 data -> low mantissa halves -> random bf16 exponents -> max>100 w.p. ~1.
// bf16 data here (|x|<6) -> max<10. All threads same samples -> uniform branch.
__device__ __forceinline__ u32 sniffp(const void* p){
    const u16* s = (const u16*)p;
    float m = 0.f;
    #pragma unroll
    for (int k=0; k<64; k++) m = fmaxf(m, fabsf(bf2f(s[2*k])));
    return (m > 100.f) ? 1u : 0u;
}

// unpack 8 bf16 (uint4) -> 2x float4
__device__ __forceinline__ void ub2(const uint4& u, float4& f0, float4& f1){
    f0 = make_float4(lof(u.x), hif(u.x), lof(u.y), hif(u.y));
    f1 = make_float4(lof(u.z), hif(u.z), lof(u.w), hif(u.w));
}

// 16-k dot step for two output columns sharing one X broadcast read.
// xp: LDS broadcast (uniform addr across wave) — 4x ds_read_b128.
// a0..a3 / b0..b3: W[colA][k..k+16), W[colB][k..k+16) in registers.
__device__ __forceinline__ void fma16x2(const float* xp,
    const float4& a0, const float4& a1, const float4& a2, const float4& a3,
    const float4& b0, const float4& b1, const float4& b2, const float4& b3,
    float& A, float& B)
{
    float4 x0 = *(const float4*)(xp);
    float4 x1 = *(const float4*)(xp+4);
    float4 x2 = *(const float4*)(xp+8);
    float4 x3 = *(const float4*)(xp+12);
    A += x0.x*a0.x; A += x0.y*a0.y; A += x0.z*a0.z; A += x0.w*a0.w;
    A += x1.x*a1.x; A += x1.y*a1.y; A += x1.z*a1.z; A += x1.w*a1.w;
    A += x2.x*a2.x; A += x2.y*a2.y; A += x2.z*a2.z; A += x2.w*a2.w;
    A += x3.x*a3.x; A += x3.y*a3.y; A += x3.z*a3.z; A += x3.w*a3.w;
    B += x0.x*b0.x; B += x0.y*b0.y; B += x0.z*b0.z; B += x0.w*b0.w;
    B += x1.x*b1.x; B += x1.y*b1.y; B += x1.z*b1.z; B += x1.w*b1.w;
    B += x2.x*b2.x; B += x2.y*b2.y; B += x2.z*b2.z; B += x2.w*b2.w;
    B += x3.x*b3.x; B += x3.y*b3.y; B += x3.z*b3.z; B += x3.w*b3.w;
}

// ============ K1: QKV projection + per-head norm + centroid bins ============
// grid (256, 3): 8 tokens/block, y: 0=Q 1=K 2=V. block 256 (4 waves).
// GEMM: ROUND-1 VERIFIED (7 restructures all lost — closed): X-tile
// broadcast from LDS; W streamed GLOBAL->REGISTER (cols t, t+256) with 16-k
// ping-pong prefetch. Scan v8 (round-9 verified): ps stride 68, b128 row
// reads. ubuf 4352 floats (round-11).
__global__ __launch_bounds__(256) void projqkv_kernel(
    const void* __restrict__ Xq, const void* __restrict__ Xk, const void* __restrict__ Xv,
    const void* __restrict__ Wq, const void* __restrict__ bq,
    const void* __restrict__ Wk, const void* __restrict__ bk,
    const void* __restrict__ Wv, const void* __restrict__ bv,
    const void* __restrict__ cen,
    void* __restrict__ outQ,                 // d_out: normalized Q staging (out dtype)
    u16* __restrict__ Kb, u16* __restrict__ Vb,
    u16* __restrict__ qbin, u16* __restrict__ kbin)
{
    int which = blockIdx.y;
    const void *X, *W, *Bb;
    if (which==0){ X=Xq; W=Wq; Bb=bq; }
    else if (which==1){ X=Xk; W=Wk; Bb=bk; }
    else { X=Xv; W=Wv; Bb=bv; }
    u32 fx = sniffp(X), fw = sniffp(W), fb = sniffp(Bb);
    int r0 = blockIdx.x * 8;
    int t = threadIdx.x;

    __shared__ __align__(16) float ubuf[4352];  // scan cent tiles [dim 64][68] (max idx 4347)
    __shared__ __align__(16) float ps[64*68];   // results [(tok*8+head)][68]; first 4128
                                                // floats alias X-stage [8][516] during GEMM
    __shared__ float nrm2[64][4];
    __shared__ float invn[64];
    __shared__ float bvl[64][8];
    __shared__ int   bil[64][8];

    float* xstage = ps;
    // Phase A: stage X tile (8 x 512), coalesced 16B/lane
    for (int i=t; i<1024; i+=256){
        int row = i>>7, c4 = i&127;
        float4 v;
        if (!fx){
            const u32* xp = (const u32*)((const u16*)X + (size_t)(r0+row)*EMBED);
            u32 a = xp[c4*2], b = xp[c4*2+1];
            v = make_float4(lof(a), hif(a), lof(b), hif(b));
        } else {
            v = ((const float4*)((const float*)X + (size_t)(r0+row)*EMBED))[c4];
        }
        *(float4*)(xstage + row*516 + c4*4) = v;
    }
    __syncthreads();                     // xstage ready

    float acc2[8][2];
    #pragma unroll
    for (int r=0;r<8;r++){ acc2[r][0]=0.f; acc2[r][1]=0.f; }

    if (fw){
        const float* w1 = (const float*)W + (size_t)t*EMBED;
        const float* w2 = (const float*)W + (size_t)(t+256)*EMBED;
        float4 pa0 = *(const float4*)(w1+ 0), pa1 = *(const float4*)(w1+ 4),
               pa2 = *(const float4*)(w1+ 8), pa3 = *(const float4*)(w1+12);
        float4 pb0 = *(const float4*)(w2+ 0), pb1 = *(const float4*)(w2+ 4),
               pb2 = *(const float4*)(w2+ 8), pb3 = *(const float4*)(w2+12);
        #pragma unroll 1
        for (int k0=0; k0<512; k0+=32){
            float4 qa0 = *(const float4*)(w1+k0+16), qa1 = *(const float4*)(w1+k0+20),
                   qa2 = *(const float4*)(w1+k0+24), qa3 = *(const float4*)(w1+k0+28);
            float4 qb0 = *(const float4*)(w2+k0+16), qb1 = *(const float4*)(w2+k0+20),
                   qb2 = *(const float4*)(w2+k0+24), qb3 = *(const float4*)(w2+k0+28);
            #pragma unroll
            for (int r=0;r<8;r++)
                fma16x2(xstage + r*516 + k0, pa0,pa1,pa2,pa3, pb0,pb1,pb2,pb3,
                        acc2[r][0], acc2[r][1]);
            if (k0+32 < 512){
                pa0 = *(const float4*)(w1+k0+32); pa1 = *(const float4*)(w1+k0+36);
                pa2 = *(const float4*)(w1+k0+40); pa3 = *(const float4*)(w1+k0+44);
                pb0 = *(const float4*)(w2+k0+32); pb1 = *(const float4*)(w2+k0+36);
                pb2 = *(const float4*)(w2+k0+40); pb3 = *(const float4*)(w2+k0+44);
            }
            #pragma unroll
            for (int r=0;r<8;r++)
                fma16x2(xstage + r*516 + k0+16, qa0,qa1,qa2,qa3, qb0,qb1,qb2,qb3,
                        acc2[r][0], acc2[r][1]);
        }
    } else {
        const uint4* w1 = (const uint4*)((const u16*)W + (size_t)t*EMBED);
        const uint4* w2 = (const uint4*)((const u16*)W + (size_t)(t+256)*EMBED);
        uint4 pa0 = w1[0], pa1 = w1[1], pb0 = w2[0], pb1 = w2[1];
        #pragma unroll 1
        for (int k0=0; k0<512; k0+=32){
            int u = k0>>3;
            uint4 qa0 = w1[u+2], qa1 = w1[u+3], qb0 = w2[u+2], qb1 = w2[u+3];
            float4 a0,a1,a2,a3,b0,b1,b2,b3;
            ub2(pa0,a0,a1); ub2(pa1,a2,a3); ub2(pb0,b0,b1); ub2(pb1,b2,b3);
            #pragma unroll
            for (int r=0;r<8;r++)
                fma16x2(xstage + r*516 + k0, a0,a1,a2,a3, b0,b1,b2,b3,
                        acc2[r][0], acc2[r][1]);
            if (k0+32 < 512){ pa0 = w1[u+4]; pa1 = w1[u+5]; pb0 = w2[u+4]; pb1 = w2[u+5]; }
            ub2(qa0,a0,a1); ub2(qa1,a2,a3); ub2(qb0,b0,b1); ub2(qb1,b2,b3);
            #pragma unroll
            for (int r=0;r<8;r++)
                fma16x2(xstage + r*516 + k0+16, a0,a1,a2,a3, b0,b1,b2,b3,
                        acc2[r][0], acc2[r][1]);
        }
    }
    __syncthreads();                     // all xstage reads done before ps overwrite
    {
        float b0 = fb ? ((const float*)Bb)[t]     : bf2f(((const u16*)Bb)[t]);
        float b1 = fb ? ((const float*)Bb)[t+256] : bf2f(((const u16*)Bb)[t+256]);
        int h0 = t>>6, c0 = t&63, h1 = (t+256)>>6, c1 = (t+256)&63;
        #pragma unroll
        for (int r=0;r<8;r++){
            ps[(r*8+h0)*68 + c0] = acc2[r][0]+b0;
            ps[(r*8+h1)*68 + c1] = acc2[r][1]+b1;
        }
    }
    __syncthreads();

    if (which == 2){
        // V: store raw bf16, 16 elems/thread
        int hr = t>>2, q4 = t&3;
        int row = hr>>3, head = hr&7;
        const float* src = ps + hr*68 + q4*16;
        u16* dst = Vb + (size_t)(r0+row)*EMBED + head*64 + q4*16;
        #pragma unroll
        for (int j8=0;j8<2;j8++){
            uint4 v;
            v.x = pack2(src[j8*8+0],src[j8*8+1]); v.y = pack2(src[j8*8+2],src[j8*8+3]);
            v.z = pack2(src[j8*8+4],src[j8*8+5]); v.w = pack2(src[j8*8+6],src[j8*8+7]);
            ((uint4*)dst)[j8] = v;
        }
        return;
    }

    // ---------- centroid scan: register-tiled LDS GEMM + argmax, tile prefetch ----------
    u32 fc = sniffp(cen);
    int rg = t>>3, cg = t&7;             // rows {2rg, 2rg+1}, cents cg*8..cg*8+7 per tile
    float best[2] = {-3.4e38f,-3.4e38f};
    int   bidx[2] = {0,0};
    float cpre[16];
    #pragma unroll
    for (int it=0; it<16; it++){
        int e = t + it*256, j = e>>6, k = e&63;
        cpre[it] = fc ? ((const float*)cen)[(size_t)j*HD + k]
                      : bf2f(((const u16*)cen)[(size_t)j*HD + k]);
    }
    for (int tt=0; tt<8; tt++){
        __syncthreads();                 // prev tile consumed (tt=0: ubuf free post-GEMM)
        #pragma unroll
        for (int it=0; it<16; it++){
            int e = t + it*256, j = e>>6, k = e&63;
            ubuf[k*68 + j] = cpre[it];
        }
        if (tt < 7){
            #pragma unroll
            for (int it=0; it<16; it++){
                int e = t + it*256, j = e>>6, k = e&63;
                int gj = (tt+1)*64 + j;
                cpre[it] = fc ? ((const float*)cen)[(size_t)gj*HD + k]
                              : bf2f(((const u16*)cen)[(size_t)gj*HD + k]);
            }
        }
        __syncthreads();
        float acc[2][8];
        #pragma unroll
        for (int j=0;j<2;j++)
            #pragma unroll
            for (int c=0;c<8;c++) acc[j][c]=0.f;
        const float* pr0 = ps + (2*rg)*68;
        const float* pr1 = pr0 + 68;
        #pragma unroll 1
        for (int k4=0;k4<64;k4+=4){
            float4 ra = *(const float4*)(pr0 + k4);     // b128 row reads
            float4 rb = *(const float4*)(pr1 + k4);
            const float* cbase = ubuf + k4*68 + cg*8;
            #define SCANK(OFF, AX, BX) { \
                const float4* cp = (const float4*)(cbase + (OFF)); \
                float4 c0 = cp[0], c1 = cp[1]; \
                acc[0][0]+=(AX)*c0.x; acc[0][1]+=(AX)*c0.y; acc[0][2]+=(AX)*c0.z; acc[0][3]+=(AX)*c0.w; \
                acc[0][4]+=(AX)*c1.x; acc[0][5]+=(AX)*c1.y; acc[0][6]+=(AX)*c1.z; acc[0][7]+=(AX)*c1.w; \
                acc[1][0]+=(BX)*c0.x; acc[1][1]+=(BX)*c0.y; acc[1][2]+=(BX)*c0.z; acc[1][3]+=(BX)*c0.w; \
                acc[1][4]+=(BX)*c1.x; acc[1][5]+=(BX)*c1.y; acc[1][6]+=(BX)*c1.z; acc[1][7]+=(BX)*c1.w; }
            SCANK(0,   ra.x, rb.x)
            SCANK(68,  ra.y, rb.y)
            SCANK(136, ra.z, rb.z)
            SCANK(204, ra.w, rb.w)
            #undef SCANK
        }
        #pragma unroll
        for (int j=0;j<2;j++){
            #pragma unroll
            for (int c=0;c<8;c++){
                int gi = tt*64 + cg*8 + c;   // ascending in-thread -> strict > keeps first
                if (acc[j][c] > best[j]){ best[j]=acc[j][c]; bidx[j]=gi; }
            }
        }
    }
    bvl[2*rg  ][cg]=best[0]; bil[2*rg  ][cg]=bidx[0];
    bvl[2*rg+1][cg]=best[1]; bil[2*rg+1][cg]=bidx[1];
    {
        int hr = t>>2, q4 = t&3;
        const float* src = ps + hr*68 + q4*16;
        float ss=0.f;
        #pragma unroll
        for (int d=0;d<16;d++) ss += src[d]*src[d];
        nrm2[hr][q4]=ss;
    }
    __syncthreads();
    if (t < 64){
        int hr = t;
        invn[hr] = 1.f / fmaxf(sqrtf(nrm2[hr][0]+nrm2[hr][1]+nrm2[hr][2]+nrm2[hr][3]), 1e-12f);
        float bv = bvl[hr][0]; int bi = bil[hr][0];
        #pragma unroll
        for (int g=1; g<8; g++){         // disjoint index sets: (>, ==&&<) merge = np.argmax
            float ov = bvl[hr][g]; int oi = bil[hr][g];
            if (ov > bv || (ov == bv && oi < bi)){ bv = ov; bi = oi; }
        }
        u16* bins = (which==0) ? qbin : kbin;
        int token = r0 + (hr>>3), head = hr&7;
        bins[head*NTOK + token] = (u16)bi;
    }
    __syncthreads();
    {
        int hr = t>>2, q4 = t&3;
        float inv = invn[hr];
        const float* src = ps + hr*68 + q4*16;
        int row = hr>>3, head = hr&7;
        size_t off = (size_t)(r0+row)*EMBED + head*64 + q4*16;
        if (which == 1){
            u16* dst = Kb + off;
            #pragma unroll
            for (int j8=0;j8<2;j8++){
                uint4 v;
                v.x = pack2(src[j8*8+0]*inv, src[j8*8+1]*inv);
                v.y = pack2(src[j8*8+2]*inv, src[j8*8+3]*inv);
                v.z = pack2(src[j8*8+4]*inv, src[j8*8+5]*inv);
                v.w = pack2(src[j8*8+6]*inv, src[j8*8+7]*inv);
                ((uint4*)dst)[j8] = v;
            }
        } else if (!fx){
            u16* dst = (u16*)outQ + off;
            #pragma unroll
            for (int j8=0;j8<2;j8++){
                uint4 v;
                v.x = pack2(src[j8*8+0]*inv, src[j8*8+1]*inv);
                v.y = pack2(src[j8*8+2]*inv, src[j8*8+3]*inv);
                v.z = pack2(src[j8*8+4]*inv, src[j8*8+5]*inv);
                v.w = pack2(src[j8*8+6]*inv, src[j8*8+7]*inv);
                ((uint4*)dst)[j8] = v;
            }
        } else {
            float* dst = (float*)outQ + off;
            #pragma unroll
            for (int j4=0;j4<4;j4++){
                float4 v = make_float4(src[j4*4+0]*inv, src[j4*4+1]*inv,
                                       src[j4*4+2]*inv, src[j4*4+3]*inv);
                ((float4*)dst)[j4] = v;
            }
        }
    }
}

// ============ K2: attention ============
// v3: grid 2048, block 512 (8 waves) — ONE head per wave (was 2 sequential
// per wave). Per-wave critical path halves; total wave-instrs unchanged;
// resident waves/CU unchanged (4 blk x 8 waves = 32). Per-head body is the
// round-8-verified code with h = wave. sel/sc wave-local -> no barriers
// after qs staging; register-softmax fast path for L<=64 (typical L~Po(12));
// LDS slow path for L>64 / fallback.
__global__ __launch_bounds__(512) void attn_kernel(
    const void* __restrict__ query,
    const u16* __restrict__ Kb, const u16* __restrict__ Vb,
    const u16* __restrict__ qbin, const u16* __restrict__ kbin,
    void* __restrict__ out)
{
    u32 fq = sniffp(query);
    int q = blockIdx.x, t = threadIdx.x;
    int wave = t>>6, lane = t&63;
    __shared__ float qs[512];
    __shared__ float sc[8][256];
    __shared__ u16   sel[8][256];

    if (!fq){
        qs[t] = bf2f(((const u16*)out)[(size_t)q*EMBED + t]);
    } else {
        qs[t] = ((const float*)out)[(size_t)q*EMBED + t];
    }
    __syncthreads();                 // qs ready (only block-wide dependency)

    int h = wave;
    {
        int myqb = qbin[h*NTOK + q];
        const uint4* kbp = (const uint4*)(kbin + h*NTOK + lane*32);
        u32 fl = 0;
        #pragma unroll
        for (int w4=0; w4<4; w4++){
            uint4 kw = kbp[w4];
            u32 arr[4] = {kw.x, kw.y, kw.z, kw.w};
            #pragma unroll
            for (int e=0;e<4;e++){
                int b0 = (int)(arr[e] & 0xffff), b1 = (int)(arr[e] >> 16);
                int d0 = (myqb - b0) & (NBINS-1), d1 = (myqb - b1) & (NBINS-1);
                if (d0 <= 1 || d0 >= NBINS-1) fl |= 1u << (w4*8 + e*2);
                if (d1 <= 1 || d1 >= NBINS-1) fl |= 1u << (w4*8 + e*2 + 1);
            }
        }
        int cnt = __popc(fl);
        int sum = cnt;
        #pragma unroll
        for (int off=1; off<64; off<<=1){
            int v = __shfl_up(sum, off, 64);
            if (lane >= off) sum += v;
        }
        int total = __shfl(sum, 63, 64);
        int r = sum - cnt;
        if (total){
            u32 f2 = fl;
            while (f2){
                int j = __ffs(f2) - 1; f2 &= f2 - 1;
                if (r < MAXSEL) sel[wave][r] = (u16)(lane*32 + j);
                r++;
            }
        } else {
            #pragma unroll
            for (int kq=0;kq<4;kq++) sel[wave][lane*4+kq] = (u16)(lane*4+kq);
        }
        int L = total ? min(total, MAXSEL) : MAXSEL;
        // in-wave fence: sel writes (cross-lane) complete before reads
        __asm__ volatile("s_waitcnt lgkmcnt(0)" ::: "memory");
        const float* qh = qs + h*64;

        if (L <= 64){
            // ---------- register softmax fast path ----------
            int kkey = 0;
            float s = -3.4e38f;
            if (lane < L){
                kkey = sel[wave][lane];
                const uint4* kr = (const uint4*)(Kb + (size_t)kkey*EMBED + h*64);
                float acc = 0.f;
                #pragma unroll
                for (int p=0;p<8;p++){ uint4 u = kr[p]; fma8(qh+p*8, u.x,u.y,u.z,u.w, acc); }
                s = acc * 0.125f;
            }
            float mloc = s;
            #pragma unroll
            for (int off=32; off; off>>=1) mloc = fmaxf(mloc, __shfl_xor(mloc, off, 64));
            float e = (lane < L) ? __expf(s - mloc) : 0.f;
            float ssum = e;
            #pragma unroll
            for (int off=32; off; off>>=1) ssum += __shfl_xor(ssum, off, 64);
            float inv = 1.f / fmaxf(ssum, 1e-37f);
            const u16* vb = Vb + h*64 + lane;
            float acc = 0.f;
            int j = 0;
            for (; j+4<=L; j+=4){
                float e0 = __shfl(e, j,   64), e1 = __shfl(e, j+1, 64);
                float e2 = __shfl(e, j+2, 64), e3 = __shfl(e, j+3, 64);
                int   k0 = __shfl(kkey, j,   64), k1 = __shfl(kkey, j+1, 64);
                int   k2 = __shfl(kkey, j+2, 64), k3 = __shfl(kkey, j+3, 64);
                float v0 = bf2f(vb[(size_t)k0*EMBED]);
                float v1 = bf2f(vb[(size_t)k1*EMBED]);
                float v2 = bf2f(vb[(size_t)k2*EMBED]);
                float v3 = bf2f(vb[(size_t)k3*EMBED]);
                acc += e0*v0; acc += e1*v1; acc += e2*v2; acc += e3*v3;
            }
            for (; j<L; j++){
                float ej = __shfl(e, j, 64);
                int   kj = __shfl(kkey, j, 64);
                acc += ej * bf2f(vb[(size_t)kj*EMBED]);
            }
            float o = acc * inv;
            if (!fq) ((u16*)out)[(size_t)q*EMBED + h*64 + lane] = f2b(o);
            else     ((float*)out)[(size_t)q*EMBED + h*64 + lane] = o;
        } else {
            // ---------- original LDS path (L > 64, incl. fallback 256) ----------
            float mloc = -3.4e38f;
            for (int jj=lane; jj<L; jj+=64){
                int kkey = sel[wave][jj];
                const uint4* kr = (const uint4*)(Kb + (size_t)kkey*EMBED + h*64);
                float acc = 0.f;
                #pragma unroll
                for (int p=0;p<8;p++){ uint4 u = kr[p]; fma8(qh+p*8, u.x,u.y,u.z,u.w, acc); }
                float s = acc * 0.125f;
                sc[wave][jj] = s;
                mloc = fmaxf(mloc, s);
            }
            #pragma unroll
            for (int off=32; off; off>>=1) mloc = fmaxf(mloc, __shfl_xor(mloc, off, 64));
            float ssum = 0.f;
            for (int jj=lane; jj<L; jj+=64){
                float e = __expf(sc[wave][jj] - mloc);
                sc[wave][jj] = e; ssum += e;
            }
            #pragma unroll
            for (int off=32; off; off>>=1) ssum += __shfl_xor(ssum, off, 64);
            float inv = 1.f / fmaxf(ssum, 1e-37f);
            // in-wave fence: sc writes (cross-lane reads below) complete
            __asm__ volatile("s_waitcnt lgkmcnt(0)" ::: "memory");
            float acc = 0.f;
            for (int j=0; j<L; j++){
                int kkey = sel[wave][j];
                acc += sc[wave][j] * bf2f(Vb[(size_t)kkey*EMBED + h*64 + lane]);
            }
            float o = acc * inv;
            if (!fq) ((u16*)out)[(size_t)q*EMBED + h*64 + lane] = f2b(o);
            else     ((float*)out)[(size_t)q*EMBED + h*64 + lane] = o;
        }
    }
}

// ============ K3: output projection, in place on d_out ============
// grid 256: 8 rows/block (best measured variant — round-5/7 bench). W streamed
// global->register (cols t, t+256), X broadcast from LDS.
__global__ __launch_bounds__(256) void oproj_kernel(
    void* __restrict__ out, const void* __restrict__ Wo, const void* __restrict__ bo)
{
    u32 fq = sniffp(out);                 // attn output dtype (== final out dtype)
    u32 fw = sniffp(Wo), fb = sniffp(bo);
    int r0 = blockIdx.x * 8;
    int t = threadIdx.x;
    __shared__ __align__(16) float xst[8*516];   // 16.5 KB

    // stage this block's 8 rows BEFORE any overwrite
    for (int i=t; i<1024; i+=256){
        int row = i>>7, c4 = i&127;
        float4 v;
        if (!fq){
            const u32* xp = (const u32*)((const u16*)out + (size_t)(r0+row)*EMBED);
            u32 a = xp[c4*2], b = xp[c4*2+1];
            v = make_float4(lof(a), hif(a), lof(b), hif(b));
        } else {
            v = ((const float4*)((const float*)out + (size_t)(r0+row)*EMBED))[c4];
        }
        *(float4*)(xst + row*516 + c4*4) = v;
    }
    __syncthreads();

    float acc2[8][2];
    #pragma unroll
    for (int r=0;r<8;r++){ acc2[r][0]=0.f; acc2[r][1]=0.f; }

    if (fw){
        const float* w1 = (const float*)Wo + (size_t)t*EMBED;
        const float* w2 = (const float*)Wo + (size_t)(t+256)*EMBED;
        float4 pa0 = *(const float4*)(w1+ 0), pa1 = *(const float4*)(w1+ 4),
               pa2 = *(const float4*)(w1+ 8), pa3 = *(const float4*)(w1+12);
        float4 pb0 = *(const float4*)(w2+ 0), pb1 = *(const float4*)(w2+ 4),
               pb2 = *(const float4*)(w2+ 8), pb3 = *(const float4*)(w2+12);
        #pragma unroll 1
        for (int k0=0; k0<512; k0+=32){
            float4 qa0 = *(const float4*)(w1+k0+16), qa1 = *(const float4*)(w1+k0+20),
                   qa2 = *(const float4*)(w1+k0+24), qa3 = *(const float4*)(w1+k0+28);
            float4 qb0 = *(const float4*)(w2+k0+16), qb1 = *(const float4*)(w2+k0+20),
                   qb2 = *(const float4*)(w2+k0+24), qb3 = *(const float4*)(w2+k0+28);
            #pragma unroll
            for (int r=0;r<8;r++)
                fma16x2(xst + r*516 + k0, pa0,pa1,pa2,pa3, pb0,pb1,pb2,pb3,
                        acc2[r][0], acc2[r][1]);
            if (k0+32 < 512){
                pa0 = *(const float4*)(w1+k0+32); pa1 = *(const float4*)(w1+k0+36);
                pa2 = *(const float4*)(w1+k0+40); pa3 = *(const float4*)(w1+k0+44);
                pb0 = *(const float4*)(w2+k0+32); pb1 = *(const float4*)(w2+k0+36);
                pb2 = *(const float4*)(w2+k0+40); pb3 = *(const float4*)(w2+k0+44);
            }
            #pragma unroll
            for (int r=0;r<8;r++)
                fma16x2(xst + r*516 + k0+16, qa0,qa1,qa2,qa3, qb0,qb1,qb2,qb3,
                        acc2[r][0], acc2[r][1]);
        }
    } else {
        const uint4* w1 = (const uint4*)((const u16*)Wo + (size_t)t*EMBED);
        const uint4* w2 = (const uint4*)((const u16*)Wo + (size_t)(t+256)*EMBED);
        uint4 pa0 = w1[0], pa1 = w1[1], pb0 = w2[0], pb1 = w2[1];
        #pragma unroll 1
        for (int k0=0; k0<512; k0+=32){
            int u = k0>>3;
            uint4 qa0 = w1[u+2], qa1 = w1[u+3], qb0 = w2[u+2], qb1 = w2[u+3];
            float4 a0,a1,a2,a3,b0,b1,b2,b3;
            ub2(pa0,a0,a1); ub2(pa1,a2,a3); ub2(pb0,b0,b1); ub2(pb1,b2,b3);
            #pragma unroll
            for (int r=0;r<8;r++)
                fma16x2(xst + r*516 + k0, a0,a1,a2,a3, b0,b1,b2,b3,
                        acc2[r][0], acc2[r][1]);
            if (k0+32 < 512){ pa0 = w1[u+4]; pa1 = w1[u+5]; pb0 = w2[u+4]; pb1 = w2[u+5]; }
            ub2(qa0,a0,a1); ub2(qa1,a2,a3); ub2(qb0,b0,b1); ub2(qb1,b2,b3);
            #pragma unroll
            for (int r=0;r<8;r++)
                fma16x2(xst + r*516 + k0+16, a0,a1,a2,a3, b0,b1,b2,b3,
                        acc2[r][0], acc2[r][1]);
        }
    }
    float b0 = fb ? ((const float*)bo)[t]     : bf2f(((const u16*)bo)[t]);
    float b1 = fb ? ((const float*)bo)[t+256] : bf2f(((const u16*)bo)[t+256]);
    if (!fq){
        u16* o = (u16*)out;
        #pragma unroll
        for (int r=0;r<8;r++){
            o[(size_t)(r0+r)*EMBED + t]       = f2b(acc2[r][0]+b0);
            o[(size_t)(r0+r)*EMBED + t + 256] = f2b(acc2[r][1]+b1);
        }
    } else {
        float* o = (float*)out;
        #pragma unroll
        for (int r=0;r<8;r++){
            o[(size_t)(r0+r)*EMBED + t]       = acc2[r][0]+b0;
            o[(size_t)(r0+r)*EMBED + t + 256] = acc2[r][1]+b1;
        }
    }
}

extern "C" void kernel_launch(void* const* d_in, const int* in_sizes, int n_in,
                              void* d_out, int out_size, void* d_ws, size_t ws_size,
                              hipStream_t stream)
{
    const void* query = d_in[0];
    const void* key   = d_in[1];
    const void* value = d_in[2];
    const void* Wq = d_in[3];
    const void* bq = d_in[4];
    const void* Wk = d_in[5];
    const void* bk = d_in[6];
    const void* Wv = d_in[7];
    const void* bv = d_in[8];
    const void* Wo = d_in[9];
    const void* bo = d_in[10];
    const void* cen = d_in[11];

    // ws layout:
    //   [0, 32K)        qbin u16[16384]
    //   [32K, 64K)      kbin u16[16384]
    //   [64K, 64K+2M)   Kb bf16 (normalized)
    //   [64K+2M, +2M)   Vb bf16 (raw)
    char* ws = (char*)d_ws;
    u16* qbin = (u16*)ws;
    u16* kbin = (u16*)(ws + 32768);
    u16* Kb   = (u16*)(ws + 65536);
    u16* Vb   = (u16*)(ws + 65536 + (size_t)2*1024*1024);

    projqkv_kernel<<<dim3(256,3), 256, 0, stream>>>(query,key,value,Wq,bq,Wk,bk,Wv,bv,cen,
                                                    d_out,Kb,Vb,qbin,kbin);
    attn_kernel<<<2048, 512, 0, stream>>>(query,Kb,Vb,qbin,kbin,d_out);
    oproj_kernel<<<256, 256, 0, stream>>>(d_out,Wo,bo);
}